// Round 3
// baseline (7644.666 us; speedup 1.0000x reference)
//
#include <hip/hip_runtime.h>
#include <math.h>

// ---------------------------------------------------------------------------
// Transpose all 32 weight matrices: wt[mat][c][k] = W[mat>>1][k][c]  (f32)
// mat = (l*8+t)*2 + which (0=Wl, 1=Wr)
// ---------------------------------------------------------------------------
__global__ __launch_bounds__(256) void transpose_w(
    const float* __restrict__ Wl, const float* __restrict__ Wr,
    float* __restrict__ wt)
{
  int elem = blockIdx.x * 256 + threadIdx.x;   // 0 .. 32*16384-1
  int mat = elem >> 14;
  int c = (elem >> 7) & 127;
  int k = elem & 127;
  const float* srcb = (mat & 1) ? Wr : Wl;
  int m2 = mat >> 1;
  wt[elem] = srcb[((long)m2 << 14) + (k << 7) + c];
}

// ---------------------------------------------------------------------------
// VALU projection: out[N,128] = x[N,128] @ W[128,128], W given transposed
// wt[c][k]. Block = 256 threads, 32 rows/block; x rows staged in LDS; LDS
// reads are wave-uniform broadcasts (conflict-free). ACC: accumulate into out.
// ---------------------------------------------------------------------------
template<bool ACC>
__global__ __launch_bounds__(256) void proj_valu(
    const float* __restrict__ xg, const float* __restrict__ wtg,
    float* __restrict__ out, int N)
{
  __shared__ __align__(16) float xs[32][128];
  const int tid = threadIdx.x;
  const long r0 = (long)blockIdx.x * 32;
  for (int i = tid; i < 512; i += 256) {        // 32 rows x 16 chunks of 8
    int r = i >> 4, k0 = (i & 15) << 3;
    float4 a = {0.f, 0.f, 0.f, 0.f}, b = {0.f, 0.f, 0.f, 0.f};
    if (r0 + r < N) {
      a = *(const float4*)(xg + (r0 + r) * 128 + k0);
      b = *(const float4*)(xg + (r0 + r) * 128 + k0 + 4);
    }
    *(float4*)&xs[r][k0] = a;
    *(float4*)&xs[r][k0 + 4] = b;
  }
  __syncthreads();
  const int c = tid & 127, rh = tid >> 7;
  float acc[16];
#pragma unroll
  for (int r = 0; r < 16; ++r) acc[r] = 0.f;
  for (int kc = 0; kc < 16; ++kc) {
    int k = kc << 3;
    float4 wa = *(const float4*)(wtg + c * 128 + k);
    float4 wb = *(const float4*)(wtg + c * 128 + k + 4);
#pragma unroll
    for (int r = 0; r < 16; ++r) {
      const float* xr = &xs[rh * 16 + r][k];
      float4 xa = *(const float4*)xr;
      float4 xb = *(const float4*)(xr + 4);
      acc[r] = fmaf(xa.x, wa.x, fmaf(xa.y, wa.y, fmaf(xa.z, wa.z, fmaf(xa.w, wa.w,
               fmaf(xb.x, wb.x, fmaf(xb.y, wb.y, fmaf(xb.z, wb.z, fmaf(xb.w, wb.w, acc[r]))))))));
    }
  }
#pragma unroll
  for (int r = 0; r < 16; ++r) {
    long row = r0 + rh * 16 + r;
    if (row < N) {
      if (ACC) out[row * 128 + c] += acc[r];
      else     out[row * 128 + c]  = acc[r];
    }
  }
}

// ---------------------------------------------------------------------------
// Edge pass A: a[e,h] = exp(sum_c lrelu(hs[src]+hd[dst]) * att);  s[dst,h] += a
// 16 lanes per edge (8 channels each); head = j>>1.
// ---------------------------------------------------------------------------
__global__ __launch_bounds__(256) void edge_logits(
    const int* __restrict__ src, const int* __restrict__ dst,
    const float* __restrict__ hs, const float* __restrict__ hd,
    const float* __restrict__ att,
    float* __restrict__ av, float* __restrict__ ssum, int E)
{
  __shared__ __align__(16) float attl[128];
  if (threadIdx.x < 128) attl[threadIdx.x] = att[threadIdx.x];
  __syncthreads();
  long idx = (long)blockIdx.x * 256 + threadIdx.x;
  int e = (int)(idx >> 4), j = (int)(idx & 15);
  if (e >= E) return;
  long si = src[e], di = dst[e];
  const float* hsr = hs + si * 128 + j * 8;
  const float* hdr = hd + di * 128 + j * 8;
  float4 s0 = *(const float4*)hsr, s1 = *(const float4*)(hsr + 4);
  float4 d0 = *(const float4*)hdr, d1 = *(const float4*)(hdr + 4);
  const float* ap = attl + j * 8;
  float p = 0.f, v;
  v = s0.x + d0.x; p += fmaxf(v, 0.2f * v) * ap[0];
  v = s0.y + d0.y; p += fmaxf(v, 0.2f * v) * ap[1];
  v = s0.z + d0.z; p += fmaxf(v, 0.2f * v) * ap[2];
  v = s0.w + d0.w; p += fmaxf(v, 0.2f * v) * ap[3];
  v = s1.x + d1.x; p += fmaxf(v, 0.2f * v) * ap[4];
  v = s1.y + d1.y; p += fmaxf(v, 0.2f * v) * ap[5];
  v = s1.z + d1.z; p += fmaxf(v, 0.2f * v) * ap[6];
  v = s1.w + d1.w; p += fmaxf(v, 0.2f * v) * ap[7];
  p += __shfl_xor(p, 1);
  if ((j & 1) == 0) {
    float a = expf(fminf(p, 60.f));   // clamp is semantics-preserving for sane data
    av[(long)e * 8 + (j >> 1)] = a;
    atomicAdd(ssum + di * 8 + (j >> 1), a);
  }
}

// ---------------------------------------------------------------------------
// Edge pass B: agg[dst] += hs[src] * (a / (s[dst]+1e-16)); 32 lanes/edge.
// ---------------------------------------------------------------------------
__global__ __launch_bounds__(256) void edge_scatter(
    const int* __restrict__ src, const int* __restrict__ dst,
    const float* __restrict__ hs, const float* __restrict__ av,
    const float* __restrict__ ssum, float* __restrict__ agg, int E)
{
  long idx = (long)blockIdx.x * 256 + threadIdx.x;
  int e = (int)(idx >> 5), lane = (int)(idx & 31);
  if (e >= E) return;
  long si = src[e], di = dst[e];
  int h = lane >> 2;
  float alpha = av[(long)e * 8 + h] / (ssum[di * 8 + h] + 1e-16f);
  float4 v = *(const float4*)(hs + si * 128 + lane * 4);
  float* dp = agg + di * 128 + lane * 4;
  atomicAdd(dp + 0, v.x * alpha);
  atomicAdd(dp + 1, v.y * alpha);
  atomicAdd(dp + 2, v.z * alpha);
  atomicAdd(dp + 3, v.w * alpha);
}

// ---------------------------------------------------------------------------
// x = LayerNorm(x + elu(agg + sum_masked(bias)));  1 wave per row, in place.
// ---------------------------------------------------------------------------
__global__ __launch_bounds__(256) void update_ln(
    float* __restrict__ xf, const float* __restrict__ agg,
    const float* __restrict__ biasl, int tmask,
    const float* __restrict__ gam, const float* __restrict__ bet, int N)
{
  int row = blockIdx.x * 4 + (threadIdx.x >> 6);
  int lane = threadIdx.x & 63;
  if (row >= N) return;
  float bs0 = 0.f, bs1 = 0.f;
#pragma unroll
  for (int t = 0; t < 8; ++t)
    if (tmask & (1 << t)) {
      bs0 += biasl[t * 128 + lane];
      bs1 += biasl[t * 128 + 64 + lane];
    }
  long base = (long)row * 128;
  float v0 = agg[base + lane] + bs0, v1 = agg[base + 64 + lane] + bs1;
  v0 = v0 > 0.f ? v0 : expf(v0) - 1.f;
  v1 = v1 > 0.f ? v1 : expf(v1) - 1.f;
  float x0 = xf[base + lane] + v0, x1 = xf[base + 64 + lane] + v1;
  float s = x0 + x1;
#pragma unroll
  for (int o = 32; o > 0; o >>= 1) s += __shfl_xor(s, o);
  float mu = s * 0.0078125f;
  float dd0 = x0 - mu, dd1 = x1 - mu;
  float q = dd0 * dd0 + dd1 * dd1;
#pragma unroll
  for (int o = 32; o > 0; o >>= 1) q += __shfl_xor(q, o);
  float r = rsqrtf(q * 0.0078125f + 1e-5f);
  xf[base + lane]      = dd0 * r * gam[lane]      + bet[lane];
  xf[base + 64 + lane] = dd1 * r * gam[64 + lane] + bet[64 + lane];
}

// ---------------------------------------------------------------------------
// zpre[64,128] += scale * batch[64,N] @ x[N,128], one 64-row n-chunk per block.
// ---------------------------------------------------------------------------
__global__ __launch_bounds__(256) void zgemm(
    const float* __restrict__ batch, const float* __restrict__ x,
    float* __restrict__ zpre, int N, float scale)
{
  __shared__ __align__(16) float xl[64 * 128];
  __shared__ __align__(16) float bl[64 * 65];
  int tid = threadIdx.x;
  int n0 = blockIdx.x * 64;
  for (int i = tid; i < 64 * 128; i += 256) {
    int nn = i >> 7;
    xl[i] = (n0 + nn < N) ? x[(long)(n0 + nn) * 128 + (i & 127)] : 0.f;
  }
  for (int i = tid; i < 64 * 64; i += 256) {
    int b = i >> 6, nn = i & 63;
    bl[nn * 65 + b] = (n0 + nn < N) ? batch[(long)b * N + n0 + nn] : 0.f;
  }
  __syncthreads();
  int cg = (tid & 31) * 4;
  int bg = (tid >> 5) * 8;
  float acc[8][4] = {};
  for (int nn = 0; nn < 64; ++nn) {
    float4 xv = *(const float4*)(xl + nn * 128 + cg);
#pragma unroll
    for (int i = 0; i < 8; ++i) {
      float bv = bl[nn * 65 + bg + i];
      acc[i][0] = fmaf(bv, xv.x, acc[i][0]);
      acc[i][1] = fmaf(bv, xv.y, acc[i][1]);
      acc[i][2] = fmaf(bv, xv.z, acc[i][2]);
      acc[i][3] = fmaf(bv, xv.w, acc[i][3]);
    }
  }
#pragma unroll
  for (int i = 0; i < 8; ++i)
#pragma unroll
    for (int j = 0; j < 4; ++j)
      atomicAdd(zpre + (bg + i) * 128 + cg + j, acc[i][j] * scale);
}

// ---------------------------------------------------------------------------
// Final LayerNorm over zpre[3*64,128] -> f32 out. 1 wave/row.
// ---------------------------------------------------------------------------
__global__ __launch_bounds__(256) void final_ln(
    const float* __restrict__ zpre, const float* __restrict__ gam,
    const float* __restrict__ bet, float* __restrict__ out)
{
  int row = blockIdx.x * 4 + (threadIdx.x >> 6);
  int lane = threadIdx.x & 63;
  if (row >= 192) return;
  int ty = row >> 6;
  long base = (long)row * 128;
  float x0 = zpre[base + lane], x1 = zpre[base + 64 + lane];
  float s = x0 + x1;
#pragma unroll
  for (int o = 32; o > 0; o >>= 1) s += __shfl_xor(s, o);
  float mu = s * 0.0078125f;
  float d0 = x0 - mu, d1 = x1 - mu;
  float q = d0 * d0 + d1 * d1;
#pragma unroll
  for (int o = 32; o > 0; o >>= 1) q += __shfl_xor(q, o);
  float r = rsqrtf(q * 0.0078125f + 1e-5f);
  out[base + lane]      = d0 * r * gam[ty * 128 + lane]      + bet[ty * 128 + lane];
  out[base + 64 + lane] = d1 * r * gam[ty * 128 + 64 + lane] + bet[ty * 128 + 64 + lane];
}

// ---------------------------------------------------------------------------
extern "C" void kernel_launch(void* const* d_in, const int* in_sizes, int n_in,
                              void* d_out, int out_size, void* d_ws, size_t ws_size,
                              hipStream_t stream)
{
  const float* batchp[3] = {(const float*)d_in[0], (const float*)d_in[1],
                            (const float*)d_in[2]};
  const float* emb[3] = {(const float*)d_in[3], (const float*)d_in[4],
                         (const float*)d_in[5]};
  const float* Wl   = (const float*)d_in[6];
  const float* Wr   = (const float*)d_in[7];
  const float* att  = (const float*)d_in[8];
  const float* bias = (const float*)d_in[9];
  const float* lng  = (const float*)d_in[10];
  const float* lnb  = (const float*)d_in[11];
  const float* outg = (const float*)d_in[12];
  const float* outb = (const float*)d_in[13];
  const int* eiP[8]; int E[8];
  for (int t = 0; t < 8; ++t) { eiP[t] = (const int*)d_in[14 + t]; E[t] = in_sizes[14 + t] / 2; }
  int Nn[3] = {in_sizes[3] / 128, in_sizes[4] / 128, in_sizes[5] / 128};
  int maxN = Nn[0] > Nn[1] ? Nn[0] : Nn[1]; if (Nn[2] > maxN) maxN = Nn[2];
  int maxE = 0; for (int t = 0; t < 5; ++t) if (E[t] > maxE) maxE = E[t];
  long Ntot = (long)Nn[0] + Nn[1] + Nn[2];

  char* p = (char*)d_ws;
  auto carve = [&](size_t b) -> void* {
    void* r = (void*)p; p += (b + 255) & ~(size_t)255; return r;
  };
  float* xf[3];
  for (int ty = 0; ty < 3; ++ty) xf[ty] = (float*)carve((size_t)Nn[ty] * 128 * 4);
  float* aggAll = (float*)carve((size_t)Ntot * 128 * 4);
  float* agg[3] = {aggAll, aggAll + (long)Nn[0] * 128, aggAll + ((long)Nn[0] + Nn[1]) * 128};
  float* hsb = (float*)carve((size_t)maxN * 128 * 4);
  float* hdb = (float*)carve((size_t)maxN * 128 * 4);
  float* ab  = (float*)carve((size_t)maxE * 8 * 4);
  float* sb  = (float*)carve((size_t)maxN * 8 * 4);
  float* zpre = (float*)carve(3 * 64 * 128 * 4);
  float* wt = (float*)carve((size_t)32 * 16384 * 4);
  if ((size_t)(p - (char*)d_ws) > ws_size) return;  // workspace too small: fail loudly

  // 0) transpose weights (32 matrices of 128x128)
  transpose_w<<<2048, 256, 0, stream>>>(Wl, Wr, wt);

  // 1) x <- embeddings (f32 working copy)
  for (int ty = 0; ty < 3; ++ty)
    hipMemcpyAsync(xf[ty], emb[ty], (size_t)Nn[ty] * 128 * 4,
                   hipMemcpyDeviceToDevice, stream);

  const int SI[5] = {1, 0, 2, 0, 0};
  const int DI[5] = {0, 1, 0, 2, 0};
  const int TMASK[3] = {0x35, 0x42, 0x88};  // gene: t0,t2,t4,t5; cpg: t1,t6; mirna: t3,t7

  for (int l = 0; l < 2; ++l) {
    hipMemsetAsync(aggAll, 0, (size_t)Ntot * 128 * 4, stream);
    for (int t = 0; t < 5; ++t) {
      int si = SI[t], di = DI[t];
      int mb = (l * 8 + t) * 2;
      proj_valu<false><<<(Nn[si] + 31) / 32, 256, 0, stream>>>(
          xf[si], wt + (long)mb * 16384, hsb, Nn[si]);
      proj_valu<false><<<(Nn[di] + 31) / 32, 256, 0, stream>>>(
          xf[di], wt + (long)(mb + 1) * 16384, hdb, Nn[di]);
      hipMemsetAsync(sb, 0, (size_t)Nn[di] * 8 * 4, stream);
      int ee = E[t];
      edge_logits<<<(int)(((long)ee * 16 + 255) / 256), 256, 0, stream>>>(
          eiP[t], eiP[t] + ee, hsb, hdb, att + (long)(l * 8 + t) * 128, ab, sb, ee);
      edge_scatter<<<(int)(((long)ee * 32 + 255) / 256), 256, 0, stream>>>(
          eiP[t], eiP[t] + ee, hsb, ab, sb, agg[di], ee);
    }
    for (int t = 5; t < 8; ++t) {  // self-loop convs: agg += x @ Wl (alpha == 1 exactly)
      int ty = t - 5;
      proj_valu<true><<<(Nn[ty] + 31) / 32, 256, 0, stream>>>(
          xf[ty], wt + (long)((l * 8 + t) * 2) * 16384, agg[ty], Nn[ty]);
    }
    for (int ty = 0; ty < 3; ++ty)
      update_ln<<<(Nn[ty] + 3) / 4, 256, 0, stream>>>(
          xf[ty], agg[ty], bias + (long)l * 8 * 128, TMASK[ty],
          lng + (long)(l * 3 + ty) * 128, lnb + (long)(l * 3 + ty) * 128, Nn[ty]);
  }

  // final: z = LN(batch @ x / sqrt(N))
  hipMemsetAsync(zpre, 0, 3 * 64 * 128 * 4, stream);
  for (int ty = 0; ty < 3; ++ty) {
    float scale = (float)(1.0 / sqrt((double)Nn[ty]));
    zgemm<<<(Nn[ty] + 63) / 64, 256, 0, stream>>>(
        batchp[ty], xf[ty], zpre + ty * 64 * 128, Nn[ty], scale);
  }
  final_ln<<<48, 256, 0, stream>>>(zpre, outg, outb, (float*)d_out);
}

// Round 4
// 1909.381 us; speedup vs baseline: 4.0037x; 4.0037x over previous
//
#include <hip/hip_runtime.h>
#include <math.h>

// ---------------------------------------------------------------------------
// Transpose all 32 weight matrices: wt[mat][c][k] = W[mat>>1][k][c]  (f32)
// mat = (l*8+t)*2 + which (0=Wl, 1=Wr)
// ---------------------------------------------------------------------------
__global__ __launch_bounds__(256) void transpose_w(
    const float* __restrict__ Wl, const float* __restrict__ Wr,
    float* __restrict__ wt)
{
  int elem = blockIdx.x * 256 + threadIdx.x;   // 0 .. 32*16384-1
  int mat = elem >> 14;
  int c = (elem >> 7) & 127;
  int k = elem & 127;
  const float* srcb = (mat & 1) ? Wr : Wl;
  int m2 = mat >> 1;
  wt[elem] = srcb[((long)m2 << 14) + (k << 7) + c];
}

// ---------------------------------------------------------------------------
// VALU projection: out[N,128] = x[N,128] @ W[128,128], W given transposed
// wt[c][k]. Block = 256 threads, 32 rows/block; x rows staged in LDS; LDS
// reads are wave-uniform broadcasts (conflict-free). ACC: accumulate into out.
// ---------------------------------------------------------------------------
template<bool ACC>
__global__ __launch_bounds__(256) void proj_valu(
    const float* __restrict__ xg, const float* __restrict__ wtg,
    float* __restrict__ out, int N)
{
  __shared__ __align__(16) float xs[32][128];
  const int tid = threadIdx.x;
  const long r0 = (long)blockIdx.x * 32;
  for (int i = tid; i < 512; i += 256) {        // 32 rows x 16 chunks of 8
    int r = i >> 4, k0 = (i & 15) << 3;
    float4 a = {0.f, 0.f, 0.f, 0.f}, b = {0.f, 0.f, 0.f, 0.f};
    if (r0 + r < N) {
      a = *(const float4*)(xg + (r0 + r) * 128 + k0);
      b = *(const float4*)(xg + (r0 + r) * 128 + k0 + 4);
    }
    *(float4*)&xs[r][k0] = a;
    *(float4*)&xs[r][k0 + 4] = b;
  }
  __syncthreads();
  const int c = tid & 127, rh = tid >> 7;
  float acc[16];
#pragma unroll
  for (int r = 0; r < 16; ++r) acc[r] = 0.f;
  for (int kc = 0; kc < 16; ++kc) {
    int k = kc << 3;
    float4 wa = *(const float4*)(wtg + c * 128 + k);
    float4 wb = *(const float4*)(wtg + c * 128 + k + 4);
#pragma unroll
    for (int r = 0; r < 16; ++r) {
      const float* xr = &xs[rh * 16 + r][k];
      float4 xa = *(const float4*)xr;
      float4 xb = *(const float4*)(xr + 4);
      acc[r] = fmaf(xa.x, wa.x, fmaf(xa.y, wa.y, fmaf(xa.z, wa.z, fmaf(xa.w, wa.w,
               fmaf(xb.x, wb.x, fmaf(xb.y, wb.y, fmaf(xb.z, wb.z, fmaf(xb.w, wb.w, acc[r]))))))));
    }
  }
#pragma unroll
  for (int r = 0; r < 16; ++r) {
    long row = r0 + rh * 16 + r;
    if (row < N) {
      if (ACC) out[row * 128 + c] += acc[r];
      else     out[row * 128 + c]  = acc[r];
    }
  }
}

// ---------------------------------------------------------------------------
// CSR build step 1: degree histogram (int atomics, L2-resident)
// ---------------------------------------------------------------------------
__global__ __launch_bounds__(256) void edge_hist(
    const int* __restrict__ dst, int* __restrict__ deg, int E)
{
  int e = blockIdx.x * 256 + threadIdx.x;
  if (e < E) atomicAdd(&deg[dst[e]], 1);
}

// ---------------------------------------------------------------------------
// CSR build step 2: single-block exclusive scan of deg[0..n) ->
// row_start[0..n] and cursor[0..n) (= row_start copy for the scatter bump).
// ---------------------------------------------------------------------------
__global__ __launch_bounds__(1024) void scan_deg(
    const int* __restrict__ deg, int* __restrict__ row_start,
    int* __restrict__ cursor, int n)
{
  __shared__ int tile[1024];
  __shared__ int sbase;
  int tid = threadIdx.x;
  if (tid == 0) sbase = 0;
  __syncthreads();
  for (int chunk = 0; chunk < n; chunk += 4096) {
    int idx0 = chunk + tid * 4;
    int v[4];
#pragma unroll
    for (int j = 0; j < 4; ++j) v[j] = (idx0 + j < n) ? deg[idx0 + j] : 0;
    tile[tid] = v[0] + v[1] + v[2] + v[3];
    __syncthreads();
    for (int off = 1; off < 1024; off <<= 1) {     // Hillis-Steele inclusive
      int t = (tid >= off) ? tile[tid - off] : 0;
      __syncthreads();
      tile[tid] += t;
      __syncthreads();
    }
    int excl = sbase + ((tid > 0) ? tile[tid - 1] : 0);
#pragma unroll
    for (int j = 0; j < 4; ++j) {
      if (idx0 + j < n) { row_start[idx0 + j] = excl; cursor[idx0 + j] = excl; }
      excl += v[j];
    }
    __syncthreads();
    if (tid == 0) sbase += tile[1023];
    __syncthreads();
  }
  if (tid == 0) row_start[n] = sbase;
}

// ---------------------------------------------------------------------------
// CSR build step 3: scatter src ids into per-dst segments.
// ---------------------------------------------------------------------------
__global__ __launch_bounds__(256) void edge_fill(
    const int* __restrict__ src, const int* __restrict__ dst,
    int* __restrict__ cursor, int* __restrict__ csr_src, int E)
{
  int e = blockIdx.x * 256 + threadIdx.x;
  if (e < E) {
    int pos = atomicAdd(&cursor[dst[e]], 1);
    csr_src[pos] = src[e];
  }
}

// ---------------------------------------------------------------------------
// Fused GATv2 aggregate, one wave per dst row. Lane l owns channels 2l,2l+1;
// head h = lanes [8h,8h+8). Online softmax-free accumulation:
// agg[d] += (sum_e a_e * hs[src_e]) / (sum_e a_e + 1e-16),  a_e = exp(logit).
// No atomics; one non-atomic += per dst row.
// ---------------------------------------------------------------------------
__global__ __launch_bounds__(256) void gat_gather(
    const int* __restrict__ row_start, const int* __restrict__ csr_src,
    const float* __restrict__ hs, const float* __restrict__ hd,
    const float* __restrict__ att, float* __restrict__ agg, int Nd)
{
  int d = blockIdx.x * 4 + (threadIdx.x >> 6);
  if (d >= Nd) return;
  int lane = threadIdx.x & 63;
  float2 att2 = *(const float2*)(att + 2 * lane);
  float2 hd2 = *(const float2*)(hd + (long)d * 128 + 2 * lane);
  int beg = row_start[d], end = row_start[d + 1];
  float n0 = 0.f, n1 = 0.f, D = 0.f;
  int i = beg;
  int sNext = (i < end) ? csr_src[i] : 0;
  for (; i < end; ++i) {
    int s = sNext;
    if (i + 1 < end) sNext = csr_src[i + 1];
    float2 h = *(const float2*)(hs + (long)s * 128 + 2 * lane);
    float v0 = h.x + hd2.x, v1 = h.y + hd2.y;
    v0 = fmaxf(v0, 0.2f * v0);
    v1 = fmaxf(v1, 0.2f * v1);
    float pp = fmaf(v0, att2.x, v1 * att2.y);
    pp += __shfl_xor(pp, 1);
    pp += __shfl_xor(pp, 2);
    pp += __shfl_xor(pp, 4);          // all 8 lanes of the head now hold logit
    float a = expf(fminf(pp, 60.f));
    n0 = fmaf(a, h.x, n0);
    n1 = fmaf(a, h.y, n1);
    D += a;
  }
  float inv = 1.f / (D + 1e-16f);
  float* ap = agg + (long)d * 128 + 2 * lane;
  float2 cur = *(const float2*)ap;
  cur.x += n0 * inv;
  cur.y += n1 * inv;
  *(float2*)ap = cur;
}

// ---------------------------------------------------------------------------
// x = LayerNorm(x + elu(agg + sum_masked(bias)));  1 wave per row, in place.
// ---------------------------------------------------------------------------
__global__ __launch_bounds__(256) void update_ln(
    float* __restrict__ xf, const float* __restrict__ agg,
    const float* __restrict__ biasl, int tmask,
    const float* __restrict__ gam, const float* __restrict__ bet, int N)
{
  int row = blockIdx.x * 4 + (threadIdx.x >> 6);
  int lane = threadIdx.x & 63;
  if (row >= N) return;
  float bs0 = 0.f, bs1 = 0.f;
#pragma unroll
  for (int t = 0; t < 8; ++t)
    if (tmask & (1 << t)) {
      bs0 += biasl[t * 128 + lane];
      bs1 += biasl[t * 128 + 64 + lane];
    }
  long base = (long)row * 128;
  float v0 = agg[base + lane] + bs0, v1 = agg[base + 64 + lane] + bs1;
  v0 = v0 > 0.f ? v0 : expf(v0) - 1.f;
  v1 = v1 > 0.f ? v1 : expf(v1) - 1.f;
  float x0 = xf[base + lane] + v0, x1 = xf[base + 64 + lane] + v1;
  float s = x0 + x1;
#pragma unroll
  for (int o = 32; o > 0; o >>= 1) s += __shfl_xor(s, o);
  float mu = s * 0.0078125f;
  float dd0 = x0 - mu, dd1 = x1 - mu;
  float q = dd0 * dd0 + dd1 * dd1;
#pragma unroll
  for (int o = 32; o > 0; o >>= 1) q += __shfl_xor(q, o);
  float r = rsqrtf(q * 0.0078125f + 1e-5f);
  xf[base + lane]      = dd0 * r * gam[lane]      + bet[lane];
  xf[base + 64 + lane] = dd1 * r * gam[64 + lane] + bet[64 + lane];
}

// ---------------------------------------------------------------------------
// zpre[64,128] += scale * batch[64,N] @ x[N,128], one 64-row n-chunk per block.
// ---------------------------------------------------------------------------
__global__ __launch_bounds__(256) void zgemm(
    const float* __restrict__ batch, const float* __restrict__ x,
    float* __restrict__ zpre, int N, float scale)
{
  __shared__ __align__(16) float xl[64 * 128];
  __shared__ __align__(16) float bl[64 * 65];
  int tid = threadIdx.x;
  int n0 = blockIdx.x * 64;
  for (int i = tid; i < 64 * 128; i += 256) {
    int nn = i >> 7;
    xl[i] = (n0 + nn < N) ? x[(long)(n0 + nn) * 128 + (i & 127)] : 0.f;
  }
  for (int i = tid; i < 64 * 64; i += 256) {
    int b = i >> 6, nn = i & 63;
    bl[nn * 65 + b] = (n0 + nn < N) ? batch[(long)b * N + n0 + nn] : 0.f;
  }
  __syncthreads();
  int cg = (tid & 31) * 4;
  int bg = (tid >> 5) * 8;
  float acc[8][4] = {};
  for (int nn = 0; nn < 64; ++nn) {
    float4 xv = *(const float4*)(xl + nn * 128 + cg);
#pragma unroll
    for (int i = 0; i < 8; ++i) {
      float bv = bl[nn * 65 + bg + i];
      acc[i][0] = fmaf(bv, xv.x, acc[i][0]);
      acc[i][1] = fmaf(bv, xv.y, acc[i][1]);
      acc[i][2] = fmaf(bv, xv.z, acc[i][2]);
      acc[i][3] = fmaf(bv, xv.w, acc[i][3]);
    }
  }
#pragma unroll
  for (int i = 0; i < 8; ++i)
#pragma unroll
    for (int j = 0; j < 4; ++j)
      atomicAdd(zpre + (bg + i) * 128 + cg + j, acc[i][j] * scale);
}

// ---------------------------------------------------------------------------
// Final LayerNorm over zpre[3*64,128] -> f32 out. 1 wave/row.
// ---------------------------------------------------------------------------
__global__ __launch_bounds__(256) void final_ln(
    const float* __restrict__ zpre, const float* __restrict__ gam,
    const float* __restrict__ bet, float* __restrict__ out)
{
  int row = blockIdx.x * 4 + (threadIdx.x >> 6);
  int lane = threadIdx.x & 63;
  if (row >= 192) return;
  int ty = row >> 6;
  long base = (long)row * 128;
  float x0 = zpre[base + lane], x1 = zpre[base + 64 + lane];
  float s = x0 + x1;
#pragma unroll
  for (int o = 32; o > 0; o >>= 1) s += __shfl_xor(s, o);
  float mu = s * 0.0078125f;
  float d0 = x0 - mu, d1 = x1 - mu;
  float q = d0 * d0 + d1 * d1;
#pragma unroll
  for (int o = 32; o > 0; o >>= 1) q += __shfl_xor(q, o);
  float r = rsqrtf(q * 0.0078125f + 1e-5f);
  out[base + lane]      = d0 * r * gam[ty * 128 + lane]      + bet[ty * 128 + lane];
  out[base + 64 + lane] = d1 * r * gam[ty * 128 + 64 + lane] + bet[ty * 128 + 64 + lane];
}

// ---------------------------------------------------------------------------
extern "C" void kernel_launch(void* const* d_in, const int* in_sizes, int n_in,
                              void* d_out, int out_size, void* d_ws, size_t ws_size,
                              hipStream_t stream)
{
  const float* batchp[3] = {(const float*)d_in[0], (const float*)d_in[1],
                            (const float*)d_in[2]};
  const float* emb[3] = {(const float*)d_in[3], (const float*)d_in[4],
                         (const float*)d_in[5]};
  const float* Wl   = (const float*)d_in[6];
  const float* Wr   = (const float*)d_in[7];
  const float* att  = (const float*)d_in[8];
  const float* bias = (const float*)d_in[9];
  const float* lng  = (const float*)d_in[10];
  const float* lnb  = (const float*)d_in[11];
  const float* outg = (const float*)d_in[12];
  const float* outb = (const float*)d_in[13];
  const int* eiP[8]; int E[8];
  for (int t = 0; t < 8; ++t) { eiP[t] = (const int*)d_in[14 + t]; E[t] = in_sizes[14 + t] / 2; }
  int Nn[3] = {in_sizes[3] / 128, in_sizes[4] / 128, in_sizes[5] / 128};
  int maxN = Nn[0] > Nn[1] ? Nn[0] : Nn[1]; if (Nn[2] > maxN) maxN = Nn[2];
  long Ntot = (long)Nn[0] + Nn[1] + Nn[2];

  const int SI[5] = {1, 0, 2, 0, 0};
  const int DI[5] = {0, 1, 0, 2, 0};
  const int TMASK[3] = {0x35, 0x42, 0x88};  // gene: t0,t2,t4,t5; cpg: t1,t6; mirna: t3,t7

  char* p = (char*)d_ws;
  auto carve = [&](size_t b) -> void* {
    void* r = (void*)p; p += (b + 255) & ~(size_t)255; return r;
  };
  float* xf[3];
  for (int ty = 0; ty < 3; ++ty) xf[ty] = (float*)carve((size_t)Nn[ty] * 128 * 4);
  float* aggAll = (float*)carve((size_t)Ntot * 128 * 4);
  float* agg[3] = {aggAll, aggAll + (long)Nn[0] * 128, aggAll + ((long)Nn[0] + Nn[1]) * 128};
  float* hsb = (float*)carve((size_t)maxN * 128 * 4);
  float* hdb = (float*)carve((size_t)maxN * 128 * 4);
  float* zpre = (float*)carve(3 * 64 * 128 * 4);
  float* wt = (float*)carve((size_t)32 * 16384 * 4);
  // CSR per real edge type
  int* degAll = (int*)carve((size_t)(Nn[0] * 3 + Nn[1] + Nn[2]) * 4);
  long degTot = Nn[0] * 3 + Nn[1] + Nn[2];
  int* rs[5]; int* cur[5]; int* csrc[5];
  {
    int* dp = degAll;
    for (int t = 0; t < 5; ++t) {
      int nd = Nn[DI[t]];
      rs[t] = (int*)carve((size_t)(nd + 1) * 4);
      cur[t] = dp; dp += nd;            // deg reused as cursor
      csrc[t] = (int*)carve((size_t)E[t] * 4);
    }
  }
  if ((size_t)(p - (char*)d_ws) > ws_size) return;  // workspace too small

  // 0) transpose weights
  transpose_w<<<2048, 256, 0, stream>>>(Wl, Wr, wt);

  // 1) x <- embeddings (f32 working copy)
  for (int ty = 0; ty < 3; ++ty)
    hipMemcpyAsync(xf[ty], emb[ty], (size_t)Nn[ty] * 128 * 4,
                   hipMemcpyDeviceToDevice, stream);

  // 2) build CSR for the 5 real edge types (edge lists are launch-invariant,
  //    but rebuilt every call for determinism/graph-capture compliance)
  hipMemsetAsync(degAll, 0, degTot * 4, stream);
  for (int t = 0; t < 5; ++t) {
    int nd = Nn[DI[t]], ee = E[t];
    edge_hist<<<(ee + 255) / 256, 256, 0, stream>>>(eiP[t] + ee, cur[t], ee);
    scan_deg<<<1, 1024, 0, stream>>>(cur[t], rs[t], cur[t], nd);
    edge_fill<<<(ee + 255) / 256, 256, 0, stream>>>(eiP[t], eiP[t] + ee, cur[t], csrc[t], ee);
  }

  for (int l = 0; l < 2; ++l) {
    hipMemsetAsync(aggAll, 0, (size_t)Ntot * 128 * 4, stream);
    for (int t = 0; t < 5; ++t) {
      int si = SI[t], di = DI[t];
      int mb = (l * 8 + t) * 2;
      proj_valu<false><<<(Nn[si] + 31) / 32, 256, 0, stream>>>(
          xf[si], wt + (long)mb * 16384, hsb, Nn[si]);
      proj_valu<false><<<(Nn[di] + 31) / 32, 256, 0, stream>>>(
          xf[di], wt + (long)(mb + 1) * 16384, hdb, Nn[di]);
      gat_gather<<<(Nn[di] + 3) / 4, 256, 0, stream>>>(
          rs[t], csrc[t], hsb, hdb, att + (long)(l * 8 + t) * 128, agg[di], Nn[di]);
    }
    for (int t = 5; t < 8; ++t) {  // self-loop convs: agg += x @ Wl (alpha == 1)
      int ty = t - 5;
      proj_valu<true><<<(Nn[ty] + 31) / 32, 256, 0, stream>>>(
          xf[ty], wt + (long)((l * 8 + t) * 2) * 16384, agg[ty], Nn[ty]);
    }
    for (int ty = 0; ty < 3; ++ty)
      update_ln<<<(Nn[ty] + 3) / 4, 256, 0, stream>>>(
          xf[ty], agg[ty], bias + (long)l * 8 * 128, TMASK[ty],
          lng + (long)(l * 3 + ty) * 128, lnb + (long)(l * 3 + ty) * 128, Nn[ty]);
  }

  // final: z = LN(batch @ x / sqrt(N))
  hipMemsetAsync(zpre, 0, 3 * 64 * 128 * 4, stream);
  for (int ty = 0; ty < 3; ++ty) {
    float scale = (float)(1.0 / sqrt((double)Nn[ty]));
    zgemm<<<(Nn[ty] + 63) / 64, 256, 0, stream>>>(
        batchp[ty], xf[ty], zpre + ty * 64 * 128, Nn[ty], scale);
  }
  final_ln<<<48, 256, 0, stream>>>(zpre, outg, outb, (float*)d_out);
}